// Round 11
// baseline (1483.497 us; speedup 1.0000x reference)
//
#include <hip/hip_runtime.h>
#include <cstdint>
#include <cstddef>

typedef __attribute__((ext_vector_type(4))) int int32x4;
typedef __attribute__((ext_vector_type(16))) int int32x16;

#define DEVI __device__ __forceinline__

constexpr int M = 16384;
constexpr int N = 11008;
constexpr int K = 4096;
constexpr int BM = 256, BN = 128, BK = 64;
constexpr int NT_M = M / BM;                 // 64
constexpr int NT_N = N / BN;                 // 86
constexpr int NTILES = K / BK;               // 64
constexpr int NWG = NT_M * NT_N;             // 5504 = 8 * 688 (exact)
constexpr int ASLOT = 16384;                 // A-only ring slot (16 KB)

DEVI void gload_lds16(const void* gsrc, void* ldst) {
  __builtin_amdgcn_global_load_lds(
      (const __attribute__((address_space(1))) unsigned int*)gsrc,
      (__attribute__((address_space(3))) unsigned int*)ldst,
      16, 0, 0);
}

// ---- weight repack: int32 -> int8 in MFMA fragment order ----
// Bpk chunk ci = nchunk*128 + kc (nchunk = n/32, kc = k/32):
// lane l holds W[nchunk*32 + (l&31)][kc*32 + (l>>5)*16 .. +15]  (16 B).
__global__ __launch_bounds__(256) void pack_w_kernel(const int* __restrict__ w32,
                                                     signed char* __restrict__ bpk) {
  const int gid = blockIdx.x * 256 + threadIdx.x;
  const int l = gid & 63;
  const int ci = gid >> 6;
  const int kc = ci & 127;
  const int nc = ci >> 7;
  const int n = nc * 32 + (l & 31);
  const int kb = kc * 32 + (l >> 5) * 16;
  const int* src = w32 + (size_t)n * K + kb;
  int32x4 o;
  #pragma unroll
  for (int c = 0; c < 4; ++c) {
    const int4 v = ((const int4*)src)[c];
    o[c] = (v.x & 255) | ((v.y & 255) << 8) |
           ((v.z & 255) << 16) | ((v.w & 255) << 24);
  }
  *(int32x4*)(bpk + (size_t)gid * 16) = o;
}

// ---- per-row symmetric int8 quantization of X (row-major output) ----
__global__ __launch_bounds__(256) void quant_x_kernel(const float* __restrict__ x,
                                                      signed char* __restrict__ xq,
                                                      float* __restrict__ sx) {
  const int row = blockIdx.x;
  const int t = threadIdx.x;
  const float4* xr = (const float4*)(x + (size_t)row * K);
  float4 v[4];
  float amax = 0.f;
  #pragma unroll
  for (int c = 0; c < 4; ++c) {
    v[c] = xr[c * 256 + t];
    amax = fmaxf(amax, fmaxf(fmaxf(fabsf(v[c].x), fabsf(v[c].y)),
                             fmaxf(fabsf(v[c].z), fabsf(v[c].w))));
  }
  __shared__ float red[256];
  red[t] = amax;
  __syncthreads();
  #pragma unroll
  for (int s = 128; s >= 1; s >>= 1) {
    if (t < s) red[t] = fmaxf(red[t], red[t + s]);
    __syncthreads();
  }
  const float am = fmaxf(red[0], 1e-20f);
  const float inv = 127.f / am;
  if (t == 0) sx[row] = am * (1.f / 127.f);
  int* xq32 = (int*)(xq + (size_t)row * K);
  #pragma unroll
  for (int c = 0; c < 4; ++c) {
    int q0 = min(127, max(-127, __float2int_rn(v[c].x * inv)));
    int q1 = min(127, max(-127, __float2int_rn(v[c].y * inv)));
    int q2 = min(127, max(-127, __float2int_rn(v[c].z * inv)));
    int q3 = min(127, max(-127, __float2int_rn(v[c].w * inv)));
    xq32[c * 256 + t] = (q0 & 255) | ((q1 & 255) << 8) |
                        ((q2 & 255) << 16) | ((q3 & 255) << 24);
  }
}

// ---- 256x128 int8 GEMM: A via LDS (ring-4), B direct-to-reg (pre-packed) ----
// 4 waves, wave tile 128x64 (4x2 frags of 32x32, acc = 128 regs).
// LDS = A only: 4 slots x 16 KB = 64 KiB -> 2 INDEPENDENT blocks/CU,
// 2 waves/SIMD from different blocks (m114 TLP covers waits/barriers).
// LDS traffic/CU-tile = A writes 16 KB + A reads 64 KB < MFMA 1171 cyc.
// Per iter t: vmcnt(4) certifies A(t) [3-iter lead] + B(t) regs [1-iter];
// 4-wave barrier; BLOAD(t+1)->regs; STAGE_A(t+3); 8 ds_reads; lgkm(4)
// MFMA8(k0); lgkm(0) MFMA8(k1). vmcnt never drains to 0 until the tail.
__global__ __launch_bounds__(256, 2) void gemm_i8_kernel(const signed char* __restrict__ aq,
                                                         const signed char* __restrict__ bpk,
                                                         const float* __restrict__ sx,
                                                         const float* __restrict__ sw,
                                                         float* __restrict__ out) {
  __shared__ __align__(16) signed char smem[4 * ASLOT];   // 64 KiB (A only)

  const int t = threadIdx.x;       // 0..255
  const int w = t >> 6;            // wave 0..3
  const int l = t & 63;

  // XCD-aware swizzle (bijective: 5504 % 8 == 0); mt-fast so the ~blocks on
  // one XCD share a B panel (L2-resident) and walk A panels sequentially.
  const int bid = blockIdx.x;
  const int wg = (bid & 7) * (NWG / 8) + (bid >> 3);
  const int mt = wg & 63;          // fast axis
  const int nt = wg >> 6;          // slow axis
  const int m0 = mt * BM, n0 = nt * BN;

  // A staging: thread t stages row t, 4 k-planes (4 x 16 B).
  const signed char* srcA = aq + (size_t)(m0 + t) * K;
  const int dBase = w * 1024;      // wave-uniform dest; HW adds lane*16

#define STAGE_A(tile)                                                         \
  {                                                                           \
    signed char* sb = smem + ((tile) & 3) * ASLOT;                            \
    const int ko = (tile) * BK;                                               \
    gload_lds16(srcA + ko,      sb + dBase);                                  \
    gload_lds16(srcA + ko + 16, sb + 4096 + dBase);                           \
    gload_lds16(srcA + ko + 32, sb + 8192 + dBase);                           \
    gload_lds16(srcA + ko + 48, sb + 12288 + dBase);                          \
  }

  // B direct loads: wave (wn) owns n-chunks nt*4 + wn*2 + {0,1}.
  // frag(tile, ks, j) at bpk[((nc)*128 + tile*2 + ks)*1024 + l*16].
  const int wm = w >> 1, wn = w & 1;
  const signed char* pbB = bpk + ((size_t)(nt * 4 + wn * 2) * 128) * 1024 + l * 16;

#define BLOAD(tile, BS)                                                       \
  BS##_k0j0 = *(const int32x4*)(pbB + (size_t)(tile) * 2048);                 \
  BS##_k1j0 = *(const int32x4*)(pbB + (size_t)(tile) * 2048 + 1024);          \
  BS##_k0j1 = *(const int32x4*)(pbB + 131072 + (size_t)(tile) * 2048);        \
  BS##_k1j1 = *(const int32x4*)(pbB + 131072 + (size_t)(tile) * 2048 + 1024); \
  __builtin_amdgcn_sched_barrier(0);

  // A fragment reads: plane(2ks+lk)*4096 + row*16.
  const int lk = l >> 5;
  const int lr = l & 31;
  int aOff[4];
  #pragma unroll
  for (int i = 0; i < 4; ++i)
    aOff[i] = lk * 4096 + (wm * 128 + i * 32 + lr) * 16;

  int32x16 acc[4][2] = {};
  int32x4 aS0[4], aS1[4];
  int32x4 bA_k0j0, bA_k0j1, bA_k1j0, bA_k1j1;
  int32x4 bB_k0j0, bB_k0j1, bB_k1j0, bB_k1j1;

#define DSL(tile, ks, AF)                                                     \
  {                                                                           \
    const signed char* sb = smem + ((tile) & 3) * ASLOT + (ks) * 8192;        \
    AF[0] = *(const int32x4*)(sb + aOff[0]);                                  \
    AF[1] = *(const int32x4*)(sb + aOff[1]);                                  \
    AF[2] = *(const int32x4*)(sb + aOff[2]);                                  \
    AF[3] = *(const int32x4*)(sb + aOff[3]);                                  \
  }

#define MFMA8(AF, B0, B1)                                                     \
  __builtin_amdgcn_s_setprio(1);                                              \
  {                                                                           \
    _Pragma("unroll")                                                         \
    for (int i = 0; i < 4; ++i) {                                             \
      acc[i][0] = __builtin_amdgcn_mfma_i32_32x32x32_i8(AF[i], B0,            \
                                                        acc[i][0], 0, 0, 0);  \
      acc[i][1] = __builtin_amdgcn_mfma_i32_32x32x32_i8(AF[i], B1,            \
                                                        acc[i][1], 0, 0, 0);  \
    }                                                                         \
  }                                                                           \
  __builtin_amdgcn_s_setprio(0);

#define WAITV(n) asm volatile("s_waitcnt vmcnt(" #n ")" ::: "memory");
#define WLGKM(n)                                                              \
  asm volatile("s_waitcnt lgkmcnt(" #n ")" ::: "memory");                     \
  __builtin_amdgcn_sched_barrier(0);
#define BAR() __builtin_amdgcn_s_barrier();

#define ITER(tt, BC, BN_)                                                     \
  WAITV(4)                 /* certify A(tt) in LDS + B(tt) regs */             \
  BAR()                    /* publish A(tt); reads of A(tt-1) retired */       \
  BLOAD(tt + 1, BN_)       /* next tile's B frags -> alternate set */          \
  STAGE_A(tt + 3)          /* overwrite slot (tt-1)&3 — safe after BAR */     \
  DSL(tt, 0, aS0)                                                             \
  DSL(tt, 1, aS1)                                                             \
  WLGKM(4)                 /* k-step 0 frags ready */                          \
  MFMA8(aS0, BC##_k0j0, BC##_k0j1)                                            \
  WLGKM(0)                 /* k-step 1 frags ready */                          \
  MFMA8(aS1, BC##_k1j0, BC##_k1j1)

  // Prologue: FIFO shaped like steady state: A0,A1,B0,A2 (16 outstanding).
  STAGE_A(0) STAGE_A(1)
  BLOAD(0, bA)
  STAGE_A(2)

  for (int tt = 0; tt < 60; tt += 2) {
    ITER(tt, bA, bB)
    ITER(tt + 1, bB, bA)
  }
  ITER(60, bA, bB)          // stages A63 (last), bloads B61 -> bB
  // tt = 61: consume bB, bload B62 -> bA, no staging.
  WAITV(4) BAR()
  BLOAD(62, bA)
  DSL(61, 0, aS0) DSL(61, 1, aS1)
  WLGKM(4) MFMA8(aS0, bB_k0j0, bB_k0j1)
  WLGKM(0) MFMA8(aS1, bB_k1j0, bB_k1j1)
  // tt = 62: drain (B62 is newest), bload B63 -> bB.
  WAITV(0) BAR()
  BLOAD(63, bB)
  DSL(62, 0, aS0) DSL(62, 1, aS1)
  WLGKM(4) MFMA8(aS0, bA_k0j0, bA_k0j1)
  WLGKM(0) MFMA8(aS1, bA_k1j0, bA_k1j1)
  // tt = 63: final tile (A63 published at t=62's barrier).
  WAITV(0)
  DSL(63, 0, aS0) DSL(63, 1, aS1)
  WLGKM(4) MFMA8(aS0, bB_k0j0, bB_k0j1)
  WLGKM(0) MFMA8(aS1, bB_k1j0, bB_k1j1)

  // Epilogue: dequant + store.
  // 32x32 C/D map: col = lane&31, row = (r&3) + 8*(r>>2) + 4*(lane>>5).
  const int rbase = lk * 4;
  float swv[2];
  #pragma unroll
  for (int fj = 0; fj < 2; ++fj) swv[fj] = sw[n0 + wn * 64 + fj * 32 + lr];
  #pragma unroll
  for (int fi = 0; fi < 4; ++fi) {
    #pragma unroll
    for (int r = 0; r < 16; ++r) {
      const int row = (r & 3) + 8 * (r >> 2) + rbase;
      const int grow = m0 + wm * 128 + fi * 32 + row;
      const float sxv = sx[grow];
      float* orow = out + (size_t)grow * N + n0 + wn * 64 + lr;
      #pragma unroll
      for (int fj = 0; fj < 2; ++fj) {
        orow[fj * 32] = (float)acc[fi][fj][r] * sxv * swv[fj];
      }
    }
  }
}

extern "C" void kernel_launch(void* const* d_in, const int* in_sizes, int n_in,
                              void* d_out, int out_size, void* d_ws, size_t ws_size,
                              hipStream_t stream) {
  const float* x = (const float*)d_in[0];
  const int* w32 = (const int*)d_in[1];
  const float* wscale = (const float*)d_in[2];
  float* out = (float*)d_out;

  // workspace: Xq[M*K] int8 | Bpk[N*K] int8 | sx[M] fp32  (~112 MB)
  signed char* xq = (signed char*)d_ws;
  signed char* bpk = xq + (size_t)M * K;
  float* sx = (float*)(bpk + (size_t)N * K);

  pack_w_kernel<<<(N / 32) * 128 * 64 / 256, 256, 0, stream>>>(w32, bpk);
  quant_x_kernel<<<M, 256, 0, stream>>>(x, xq, sx);
  gemm_i8_kernel<<<NWG, 256, 0, stream>>>(xq, bpk, sx, wscale, out);
}

// Round 12
// 1063.440 us; speedup vs baseline: 1.3950x; 1.3950x over previous
//
#include <hip/hip_runtime.h>
#include <cstdint>
#include <cstddef>

typedef __attribute__((ext_vector_type(4))) int int32x4;
typedef __attribute__((ext_vector_type(16))) int int32x16;

#define DEVI __device__ __forceinline__

constexpr int M = 16384;
constexpr int N = 11008;
constexpr int K = 4096;
constexpr int BM = 256, BN = 256, BK = 64;   // BK in int8 elements (= bytes)
constexpr int NT_M = M / BM;                 // 64
constexpr int NT_N = N / BN;                 // 43
constexpr int NTILES = K / BK;               // 64
constexpr int NWG = NT_M * NT_N;             // 2752
constexpr int TILE_BYTES = BM * BK;          // 16 KB per tensor per slot

DEVI void gload_lds16(const void* gsrc, void* ldst) {
  __builtin_amdgcn_global_load_lds(
      (const __attribute__((address_space(1))) unsigned int*)gsrc,
      (__attribute__((address_space(3))) unsigned int*)ldst,
      16, 0, 0);
}

// ---- weight repack: int32 (harness int convention) -> int8 ----
__global__ __launch_bounds__(256) void pack_w_kernel(const int* __restrict__ w32,
                                                     signed char* __restrict__ w8) {
  const int idx = blockIdx.x * 256 + threadIdx.x;
  const int total4 = N * K / 4;
  if (idx < total4) {
    const int4 v = ((const int4*)w32)[idx];
    ((int*)w8)[idx] = (v.x & 255) | ((v.y & 255) << 8) |
                      ((v.z & 255) << 16) | ((v.w & 255) << 24);
  }
}

// ---- per-row symmetric int8 quantization of X ----
__global__ __launch_bounds__(256) void quant_x_kernel(const float* __restrict__ x,
                                                      signed char* __restrict__ xq,
                                                      float* __restrict__ sx) {
  const int row = blockIdx.x;
  const int t = threadIdx.x;
  const float4* xr = (const float4*)(x + (size_t)row * K);
  float4 v[4];
  float amax = 0.f;
  #pragma unroll
  for (int c = 0; c < 4; ++c) {
    v[c] = xr[c * 256 + t];
    amax = fmaxf(amax, fmaxf(fmaxf(fabsf(v[c].x), fabsf(v[c].y)),
                             fmaxf(fabsf(v[c].z), fabsf(v[c].w))));
  }
  __shared__ float red[256];
  red[t] = amax;
  __syncthreads();
  #pragma unroll
  for (int s = 128; s >= 1; s >>= 1) {
    if (t < s) red[t] = fmaxf(red[t], red[t + s]);
    __syncthreads();
  }
  const float am = fmaxf(red[0], 1e-20f);
  const float inv = 127.f / am;
  if (t == 0) sx[row] = am * (1.f / 127.f);
  int* xq32 = (int*)(xq + (size_t)row * K);
  #pragma unroll
  for (int c = 0; c < 4; ++c) {
    int q0 = min(127, max(-127, __float2int_rn(v[c].x * inv)));
    int q1 = min(127, max(-127, __float2int_rn(v[c].y * inv)));
    int q2 = min(127, max(-127, __float2int_rn(v[c].z * inv)));
    int q3 = min(127, max(-127, __float2int_rn(v[c].w * inv)));
    xq32[c * 256 + t] = (q0 & 255) | ((q1 & 255) << 8) |
                        ((q2 & 255) << 16) | ((q3 & 255) << 24);
  }
}

// ---- 256x256 int8 GEMM, ring-4 LDS, reg double-buffer (R6 body) ----
// NEW vs R6: L2-aware BAND mapping. nt processed in bands of 4 (256 blocks
// = 1/CU, fully resident). Within a band, XCD x (= bid&7, established
// swizzle technique) owns mt in [8x, 8x+8) x the band's 4 nt:
//  - B band-slice = 4 x 1 MB = L2-resident per XCD (each byte: 1 far pull,
//    7 L2 re-reads) -> B far drops 2.75 GB -> 0.35 GB.
//  - A panel shared by the 4 same-mt blocks of its XCD via L2 -> A far =
//    64 MB per band -> 0.70 GB total.
// Plus non-temporal C stores so the 704 MB output stream stops evicting
// the staged panels from L2/L3 (R6's FETCH was 14x compulsory).
__global__ __launch_bounds__(512, 2) void gemm_i8_kernel(const signed char* __restrict__ aq,
                                                         const signed char* __restrict__ wq,
                                                         const float* __restrict__ sx,
                                                         const float* __restrict__ sw,
                                                         float* __restrict__ out) {
  extern __shared__ signed char smem[];            // 131072 B: 4 slots x 32 KB
  signed char* lsA = smem;                          // 4 slots x 16 KB (A)
  signed char* lsB = smem + 4 * TILE_BYTES;         // 4 slots x 16 KB (B)

  const int t = threadIdx.x;
  const int w = t >> 6;            // wave 0..7
  const int l = t & 63;

  // Band mapping (see header comment). Bands 0..9: nt = 4b..4b+3;
  // band 10: 192 blocks, nt in {40,41,42}.
  const int bid = blockIdx.x;
  int mt, nt;
  {
    const int band = bid >> 8;         // bid / 256
    const int ib = bid & 255;
    const int x = ib & 7;              // XCD (bid % 8 round-robin)
    const int j = ib >> 3;             // 0..31 (band<10) / 0..23 (band 10)
    if (band < 10) {
      mt = x * 8 + (j >> 2);
      nt = band * 4 + (j & 3);
    } else {
      mt = x * 8 + j / 3;
      nt = 40 + j % 3;
    }
  }
  const int m0 = mt * BM, n0 = nt * BN;

  // Staging: waves 0..3 stage A, waves 4..7 stage B; 4 x 16B chunks/thread.
  const bool stA = (w < 4);
  const signed char* src[4];
  int loff[4];
  #pragma unroll
  for (int c = 0; c < 4; ++c) {
    const int q = (w & 3) * 4 + c;       // chunk id within this tensor
    const int row = (q & 3) * 64 + l;
    const int s = q >> 2;                // k-plane
    const signed char* base = stA ? (aq + (size_t)(m0 + row) * K)
                                  : (wq + (size_t)(n0 + row) * K);
    src[c] = base + s * 16;
    loff[c] = q * 1024;                  // wave-uniform dest; HW adds lane*16
  }

#define STAGE(tile)                                                           \
  {                                                                           \
    signed char* lbase = (stA ? lsA : lsB) + ((tile) & 3) * TILE_BYTES;       \
    const int koff = (tile) * BK;                                             \
    gload_lds16(src[0] + koff, lbase + loff[0]);                              \
    gload_lds16(src[1] + koff, lbase + loff[1]);                              \
    gload_lds16(src[2] + koff, lbase + loff[2]);                              \
    gload_lds16(src[3] + koff, lbase + loff[3]);                              \
  }

  // Wave output: 128x64 at (wm*128, wn*64); 4x2 frags of 32x32.
  const int wm = w >> 2, wn = w & 3;
  const int lk = l >> 5;           // k-chunk within substep (2 x 16B planes)
  const int lr = l & 31;
  int aOff[4], bOff[2];
  #pragma unroll
  for (int i = 0; i < 4; ++i)
    aOff[i] = lk * 4096 + (wm * 128 + i * 32 + lr) * 16;
  #pragma unroll
  for (int j = 0; j < 2; ++j)
    bOff[j] = lk * 4096 + (wn * 64 + j * 32 + lr) * 16;

  int32x16 acc[4][2] = {};
  int32x4 af0[4], bf0[2], af1[4], bf1[2];

#define DSL(tile, sub, AF, BF)                                                \
  {                                                                           \
    const signed char* pA = lsA + ((tile) & 3) * TILE_BYTES + (sub) * 8192;   \
    const signed char* pB = lsB + ((tile) & 3) * TILE_BYTES + (sub) * 8192;   \
    AF[0] = *(const int32x4*)(pA + aOff[0]);                                  \
    AF[1] = *(const int32x4*)(pA + aOff[1]);                                  \
    AF[2] = *(const int32x4*)(pA + aOff[2]);                                  \
    AF[3] = *(const int32x4*)(pA + aOff[3]);                                  \
    BF[0] = *(const int32x4*)(pB + bOff[0]);                                  \
    BF[1] = *(const int32x4*)(pB + bOff[1]);                                  \
  }

#define MFMA8(AF, BF)                                                         \
  __builtin_amdgcn_s_setprio(1);                                              \
  {                                                                           \
    _Pragma("unroll")                                                         \
    for (int i = 0; i < 4; ++i) {                                             \
      acc[i][0] = __builtin_amdgcn_mfma_i32_32x32x32_i8(AF[i], BF[0],         \
                                                        acc[i][0], 0, 0, 0);  \
      acc[i][1] = __builtin_amdgcn_mfma_i32_32x32x32_i8(AF[i], BF[1],         \
                                                        acc[i][1], 0, 0, 0);  \
    }                                                                         \
  }                                                                           \
  __builtin_amdgcn_s_setprio(0);

#define WAITV(n) asm volatile("s_waitcnt vmcnt(" #n ")" ::: "memory");
#define WLGKM(n)                                                              \
  asm volatile("s_waitcnt lgkmcnt(" #n ")" ::: "memory");                     \
  __builtin_amdgcn_sched_barrier(0);
#define BAR() __builtin_amdgcn_s_barrier();

#define ITER(tt)                                                              \
  WAITV(4)                  /* tile tt+1 landed (tt+2 still in flight) */      \
  BAR()                     /* publish tt+1; tt-1 reads all retired */         \
  STAGE(tt + 3)             /* overwrites slot (tt-1)&3 — safe after BAR */   \
  DSL(tt, 1, af1, bf1)      /* Read(tt.1) -> set1, overlaps MFMA below */     \
  WLGKM(6)                  /* Read(tt.0) complete */                          \
  MFMA8(af0, bf0)           /* tile tt sub0 */                                 \
  DSL(tt + 1, 0, af0, bf0)  /* Read(tt+1.0) -> set0 (tt+1 certified above) */ \
  WLGKM(6)                  /* Read(tt.1) complete */                          \
  MFMA8(af1, bf1)           /* tile tt sub1 */

  // Prologue: stage tiles 0..2 (12 loads); tile 0 landed -> read sub0.
  STAGE(0) STAGE(1) STAGE(2)
  WAITV(8)
  BAR()
  DSL(0, 0, af0, bf0)

  #pragma unroll 4
  for (int tb = 0; tb < 60; ++tb) {
    ITER(tb)
  }
  ITER(60)   // stages tile 63 (last)
  // tt = 61: tiles 62,63 outstanding (8) -> wait 62 done
  WAITV(4) BAR()
  DSL(61, 1, af1, bf1) WLGKM(6) MFMA8(af0, bf0)
  DSL(62, 0, af0, bf0) WLGKM(6) MFMA8(af1, bf1)
  // tt = 62: wait tile 63 done
  WAITV(0) BAR()
  DSL(62, 1, af1, bf1) WLGKM(6) MFMA8(af0, bf0)
  DSL(63, 0, af0, bf0) WLGKM(6) MFMA8(af1, bf1)
  // tt = 63
  DSL(63, 1, af1, bf1) WLGKM(6) MFMA8(af0, bf0)
  WLGKM(0) MFMA8(af1, bf1)

  // Epilogue: dequant + non-temporal store (don't evict panels from L2/L3).
  // 32x32 C/D map: col = lane&31, row = (r&3) + 8*(r>>2) + 4*(lane>>5).
  const int rbase = lk * 4;
  float swv[2];
  #pragma unroll
  for (int fj = 0; fj < 2; ++fj) swv[fj] = sw[n0 + wn * 64 + fj * 32 + lr];
  #pragma unroll
  for (int fi = 0; fi < 4; ++fi) {
    #pragma unroll
    for (int r = 0; r < 16; ++r) {
      const int row = (r & 3) + 8 * (r >> 2) + rbase;
      const int grow = m0 + wm * 128 + fi * 32 + row;
      const float sxv = sx[grow];
      float* orow = out + (size_t)grow * N + n0 + wn * 64 + lr;
      #pragma unroll
      for (int fj = 0; fj < 2; ++fj) {
        __builtin_nontemporal_store((float)acc[fi][fj][r] * sxv * swv[fj],
                                    &orow[fj * 32]);
      }
    }
  }
}

extern "C" void kernel_launch(void* const* d_in, const int* in_sizes, int n_in,
                              void* d_out, int out_size, void* d_ws, size_t ws_size,
                              hipStream_t stream) {
  const float* x = (const float*)d_in[0];
  const int* w32 = (const int*)d_in[1];
  const float* wscale = (const float*)d_in[2];
  float* out = (float*)d_out;

  signed char* xq = (signed char*)d_ws;
  signed char* wq = xq + (size_t)M * K;
  float* sx = (float*)(wq + (size_t)N * K);

  pack_w_kernel<<<(N * K / 4 + 255) / 256, 256, 0, stream>>>(w32, wq);
  quant_x_kernel<<<M, 256, 0, stream>>>(x, xq, sx);
  gemm_i8_kernel<<<NWG, 512, 131072, stream>>>(xq, wq, sx, wscale, out);
}